// Round 4
// baseline (877.029 us; speedup 1.0000x reference)
//
#include <hip/hip_runtime.h>
#include <hip/hip_bf16.h>
#include <stdint.h>

typedef __attribute__((ext_vector_type(8))) short short8;
typedef __attribute__((ext_vector_type(4))) float floatx4;

// load 8 f32, convert to 8 bf16 packed in a short8
__device__ __forceinline__ short8 cvt8(const float* p) {
    float4 a = *(const float4*)p;
    float4 b = *(const float4*)(p + 4);
    union { short s[8]; short8 v; } u;
    __hip_bfloat16* h = (__hip_bfloat16*)u.s;
    h[0] = __float2bfloat16(a.x); h[1] = __float2bfloat16(a.y);
    h[2] = __float2bfloat16(a.z); h[3] = __float2bfloat16(a.w);
    h[4] = __float2bfloat16(b.x); h[5] = __float2bfloat16(b.y);
    h[6] = __float2bfloat16(b.z); h[7] = __float2bfloat16(b.w);
    return u.v;
}

// ---------------------------------------------------------------- GEMM
// C = A @ Bt^T + bias.  A: [M][K] (f32 if A_BF16==0 else bf16), Bt: [N][K] f32,
// bias [N] f32.  128x128 tile, BK=32, 4 waves 2x2, synchronous staging with
// fused f32->bf16 conversion.
// STORE_MODE: 0 = f32 row-major; 1 = bf16 row-major;
//             2 = bf16 V-transpose: (row=t,col=hid) -> Vt[(b*16+nh)*128+d][s]
//                 with s=t>>2, b=t&3, nh=col>>7, d=col&127  (N must be 2048).
template <int A_BF16, int STORE_MODE>
__global__ __launch_bounds__(256, 2) void gemm_xw(const void* __restrict__ Av,
                                                  const float* __restrict__ Bt,
                                                  const float* __restrict__ bias,
                                                  void* __restrict__ Cv,
                                                  int M, int N, int K) {
    __shared__ __align__(16) __hip_bfloat16 sA[128 * 32];
    __shared__ __align__(16) __hip_bfloat16 sB[128 * 32];
    const int tid  = threadIdx.x;
    const int wave = tid >> 6, lane = tid & 63;
    const int quad = lane >> 4, l16 = lane & 15;
    const int m0 = blockIdx.x * 128, n0 = blockIdx.y * 128;
    const int wm = (wave >> 1) * 64, wn = (wave & 1) * 64;
    const int lrow = lane >> 2;        // 16 rows per wave-chunk
    const int lcol = (lane & 3) * 8;   // element offset within 32-wide row

    floatx4 acc[4][4];
#pragma unroll
    for (int i = 0; i < 4; i++)
#pragma unroll
        for (int j = 0; j < 4; j++) acc[i][j] = (floatx4)0.0f;

    for (int k0 = 0; k0 < K; k0 += 32) {
        short8 va[2], vb[2];
#pragma unroll
        for (int c = 0; c < 2; ++c) {
            int r = wave * 32 + c * 16 + lrow;
            if (A_BF16)
                va[c] = *(const short8*)((const __hip_bfloat16*)Av + (size_t)(m0 + r) * K + k0 + lcol);
            else
                va[c] = cvt8((const float*)Av + (size_t)(m0 + r) * K + k0 + lcol);
            vb[c] = cvt8(Bt + (size_t)(n0 + r) * K + k0 + lcol);
        }
        __syncthreads();  // prior iteration's fragment reads done
#pragma unroll
        for (int c = 0; c < 2; ++c) {
            int r = wave * 32 + c * 16 + lrow;
            *(short8*)((char*)sA + r * 64 + lcol * 2) = va[c];
            *(short8*)((char*)sB + r * 64 + lcol * 2) = vb[c];
        }
        __syncthreads();  // stores visible to all waves

        short8 af[4], bf[4];
#pragma unroll
        for (int i = 0; i < 4; i++)
            af[i] = *(const short8*)((const char*)sA + (wm + i * 16 + l16) * 64 + quad * 16);
#pragma unroll
        for (int j = 0; j < 4; j++)
            bf[j] = *(const short8*)((const char*)sB + (wn + j * 16 + l16) * 64 + quad * 16);
#pragma unroll
        for (int i = 0; i < 4; i++)
#pragma unroll
            for (int j = 0; j < 4; j++)
                acc[i][j] = __builtin_amdgcn_mfma_f32_16x16x32_bf16(af[i], bf[j], acc[i][j], 0, 0, 0);
    }

#pragma unroll
    for (int i = 0; i < 4; i++) {
#pragma unroll
        for (int j = 0; j < 4; j++) {
            int col  = n0 + wn + j * 16 + l16;
            float bv = bias[col];
#pragma unroll
            for (int r = 0; r < 4; ++r) {
                int row = m0 + wm + i * 16 + quad * 4 + r;  // C-layout: row=quad*4+reg
                float v = acc[i][j][r] + bv;
                if (STORE_MODE == 0) {
                    ((float*)Cv)[(size_t)row * N + col] = v;
                } else if (STORE_MODE == 1) {
                    ((__hip_bfloat16*)Cv)[(size_t)row * N + col] = __float2bfloat16(v);
                } else {
                    int s = row >> 2, b = row & 3, nh = col >> 7, d = col & 127;
                    ((__hip_bfloat16*)Cv)[((size_t)(b * 16 + nh) * 128 + d) * 2048 + s] =
                        __float2bfloat16(v);
                }
            }
        }
    }
}

// ---------------------------------------------------------------- RoPE (in-place on Q and K)
// pair p in [0,32): dims (2p,2p+1) of each head; angle = s * BASE^(-(p%16)/16)
__global__ __launch_bounds__(256) void rope_kernel(__hip_bfloat16* __restrict__ Q,
                                                   __hip_bfloat16* __restrict__ K) {
    const int PER = 8192 * 16 * 32;
    int idx = (int)blockIdx.x * 256 + (int)threadIdx.x;
    __hip_bfloat16* base = (idx < PER) ? Q : K;
    int i  = (idx < PER) ? idx : idx - PER;
    int p  = i & 31;
    int nh = (i >> 5) & 15;
    int t  = i >> 9;       // token index = s*4 + b
    int s  = t >> 2;
    float inv = __expf(-(float)(p & 15) * 0.5756462732485115f);  // ln(10000)/16
    float ang = (float)s * inv;
    float c = cosf(ang), sn = sinf(ang);
    size_t off = (size_t)t * 2048 + nh * 128 + 2 * p;
    float x0 = __bfloat162float(base[off]);
    float x1 = __bfloat162float(base[off + 1]);
    base[off]     = __float2bfloat16(x0 * c - x1 * sn);
    base[off + 1] = __float2bfloat16(x0 * sn + x1 * c);
}

// ---------------------------------------------------------------- flash attention
// Qio [t][2048] (roped; O written back in place), Kmat [t][2048] (roped),
// Vt [bh][128][2048].  Block (bh, qt): 64 q-rows, 64 kv per iter; wave w owns
// q rows w*16..w*16+15.  Each block's output region (its qt rows x its head's
// 128 cols) is exactly the Q region it staged at kernel start -> in-place safe.
__global__ __launch_bounds__(256, 2) void attn_kernel(__hip_bfloat16* __restrict__ Qio,
                                                      const __hip_bfloat16* __restrict__ Kmat,
                                                      const __hip_bfloat16* __restrict__ Vt) {
    __shared__ __align__(16) __hip_bfloat16 sQ[4][64][32];   // [d-chunk][q][32d]
    __shared__ __align__(16) __hip_bfloat16 sK[4][64][32];   // [d-chunk][kv][32d]
    __shared__ __align__(16) __hip_bfloat16 sV[2][128][32];  // [kv-chunk][d][32kv]
    __shared__ __align__(16) __hip_bfloat16 sP[2][64][32];   // [kv-chunk][q][32kv]
    const int tid  = threadIdx.x;
    const int wave = tid >> 6, lane = tid & 63;
    const int quad = lane >> 4, l16 = lane & 15;
    const int bh = blockIdx.x, b = bh >> 4, nh = bh & 15;
    const int qt = blockIdx.y;
    const int lrow = lane >> 2, lcolb = (lane & 3) * 16;
    const float scale = 0.08838834764831845f;  // 1/sqrt(128)

    // stage Q tile once (synchronous): wave w stages d-chunk w
#pragma unroll
    for (int c = 0; c < 4; ++c) {
        int qrow = c * 16 + lrow;
        int t    = (qt * 64 + qrow) * 4 + b;
        short8 v = *(const short8*)((const char*)(Qio + (size_t)t * 2048 + nh * 128 + wave * 32) + lcolb);
        *(short8*)((char*)&sQ[wave][0][0] + qrow * 64 + lcolb) = v;
    }

    float m_i[4], l_i[4];
#pragma unroll
    for (int r = 0; r < 4; ++r) { m_i[r] = -1e30f; l_i[r] = 0.f; }
    floatx4 o_acc[8];
#pragma unroll
    for (int n = 0; n < 8; ++n) o_acc[n] = (floatx4)0.0f;

    for (int kt = 0; kt <= qt; ++kt) {
        // preload K / V tiles into registers (global reads, no LDS hazard)
        short8 vk[4], vv[4];
#pragma unroll
        for (int c = 0; c < 4; ++c) {
            int krow = c * 16 + lrow;
            int t    = (kt * 64 + krow) * 4 + b;
            vk[c] = *(const short8*)((const char*)(Kmat + (size_t)t * 2048 + nh * 128 + wave * 32) + lcolb);
        }
#pragma unroll
        for (int c = 0; c < 4; ++c) {
            int d  = (wave & 1) * 64 + c * 16 + lrow;
            int kc = wave >> 1;
            vv[c] = *(const short8*)((const char*)(Vt + ((size_t)bh * 128 + d) * 2048 + kt * 64 + kc * 32) + lcolb);
        }
        __syncthreads();  // prior iteration's sK/sV/sP reads done
#pragma unroll
        for (int c = 0; c < 4; ++c) {
            int krow = c * 16 + lrow;
            *(short8*)((char*)&sK[wave][0][0] + krow * 64 + lcolb) = vk[c];
        }
#pragma unroll
        for (int c = 0; c < 4; ++c) {
            int d  = (wave & 1) * 64 + c * 16 + lrow;
            int kc = wave >> 1;
            *(short8*)((char*)&sV[kc][0][0] + d * 64 + lcolb) = vv[c];
        }
        __syncthreads();  // staging visible (also covers sQ on first iter)

        // S = Q K^T for this wave's 16 q-rows
        floatx4 sacc[4];
#pragma unroll
        for (int n = 0; n < 4; ++n) sacc[n] = (floatx4)0.0f;
#pragma unroll
        for (int kk = 0; kk < 4; ++kk) {
            short8 aq = *(const short8*)((const char*)&sQ[kk][0][0] + (wave * 16 + l16) * 64 + quad * 16);
#pragma unroll
            for (int nt = 0; nt < 4; ++nt) {
                short8 bk = *(const short8*)((const char*)&sK[kk][0][0] + (nt * 16 + l16) * 64 + quad * 16);
                sacc[nt] = __builtin_amdgcn_mfma_f32_16x16x32_bf16(aq, bk, sacc[nt], 0, 0, 0);
            }
        }

        // online softmax (C-layout: rows quad*4+r, cols nt*16+l16)
        const bool diag = (kt == qt);
        float sv[4][4], mx[4];
#pragma unroll
        for (int r = 0; r < 4; ++r) mx[r] = -1e30f;
#pragma unroll
        for (int nt = 0; nt < 4; ++nt)
#pragma unroll
            for (int r = 0; r < 4; ++r) {
                float v = sacc[nt][r] * scale;
                if (diag && (nt * 16 + l16 > wave * 16 + quad * 4 + r)) v = -1e30f;
                sv[nt][r] = v;
                mx[r] = fmaxf(mx[r], v);
            }
        // row-reduce over the 16 lanes sharing this quad (cols)
#pragma unroll
        for (int off = 1; off < 16; off <<= 1)
#pragma unroll
            for (int r = 0; r < 4; ++r) mx[r] = fmaxf(mx[r], __shfl_xor(mx[r], off, 64));

        float alpha[4], mnew[4], rsum[4];
#pragma unroll
        for (int r = 0; r < 4; ++r) {
            mnew[r]  = fmaxf(m_i[r], mx[r]);
            alpha[r] = __expf(m_i[r] - mnew[r]);
            rsum[r]  = 0.f;
        }
#pragma unroll
        for (int nt = 0; nt < 4; ++nt)
#pragma unroll
            for (int r = 0; r < 4; ++r) {
                float p = __expf(sv[nt][r] - mnew[r]);
                rsum[r] += p;
                int q  = wave * 16 + quad * 4 + r;
                int kv = nt * 16 + l16;
                sP[kv >> 5][q][kv & 31] = __float2bfloat16(p);
            }
#pragma unroll
        for (int off = 1; off < 16; off <<= 1)
#pragma unroll
            for (int r = 0; r < 4; ++r) rsum[r] += __shfl_xor(rsum[r], off, 64);
#pragma unroll
        for (int r = 0; r < 4; ++r) {
            l_i[r] = l_i[r] * alpha[r] + rsum[r];
            m_i[r] = mnew[r];
        }
#pragma unroll
        for (int n = 0; n < 8; ++n)
#pragma unroll
            for (int r = 0; r < 4; ++r) o_acc[n][r] *= alpha[r];

        __syncthreads();  // sP writes ordered & visible before PV reads

        // O += P V
#pragma unroll
        for (int kk = 0; kk < 2; ++kk) {
            short8 ap = *(const short8*)((const char*)&sP[kk][0][0] + (wave * 16 + l16) * 64 + quad * 16);
#pragma unroll
            for (int nt = 0; nt < 8; ++nt) {
                short8 bv = *(const short8*)((const char*)&sV[kk][0][0] + (nt * 16 + l16) * 64 + quad * 16);
                o_acc[nt] = __builtin_amdgcn_mfma_f32_16x16x32_bf16(ap, bv, o_acc[nt], 0, 0, 0);
            }
        }
    }

    // write O in place over this block's own Q region
#pragma unroll
    for (int nt = 0; nt < 8; ++nt)
#pragma unroll
        for (int r = 0; r < 4; ++r) {
            int s = qt * 64 + wave * 16 + quad * 4 + r;
            int t = s * 4 + b;
            int col = nh * 128 + nt * 16 + l16;
            Qio[(size_t)t * 2048 + col] = __float2bfloat16(o_acc[nt][r] / l_i[r]);
        }
}

// ---------------------------------------------------------------- launch
extern "C" void kernel_launch(void* const* d_in, const int* in_sizes, int n_in,
                              void* d_out, int out_size, void* d_ws, size_t ws_size,
                              hipStream_t stream) {
    const float* x  = (const float*)d_in[0];
    const float* wq = (const float*)d_in[1];
    const float* bq = (const float*)d_in[2];
    const float* wk = (const float*)d_in[3];
    const float* bk = (const float*)d_in[4];
    const float* wv = (const float*)d_in[5];
    const float* bv = (const float*)d_in[6];
    const float* wd = (const float*)d_in[7];
    const float* bd = (const float*)d_in[8];
    // d_in[9] = start_pos: unused (reference recomputes t=arange(seq))

    // Scratch plan (ws requirement: 32 MiB only):
    //   Qb            = d_ws[0,32MiB)   bf16 Q; attention output written in place
    //   Kb            = d_out[0,32MiB)  bf16 K scratch inside the 64MiB f32 out buffer
    //   Vt            = d_out[32,64MiB) bf16 V^T [bh][128][2048]
    // Final GEMM reads only Qb/wd and overwrites d_out with f32 output.
    __hip_bfloat16* Qb = (__hip_bfloat16*)d_ws;
    __hip_bfloat16* Kb = (__hip_bfloat16*)d_out;
    __hip_bfloat16* Vt = (__hip_bfloat16*)d_out + (size_t)16 * 1024 * 1024;

    dim3 gg(64, 16);
    gemm_xw<0, 1><<<gg, 256, 0, stream>>>(x, wq, bq, Qb, 8192, 2048, 2048);
    gemm_xw<0, 1><<<gg, 256, 0, stream>>>(x, wk, bk, Kb, 8192, 2048, 2048);
    gemm_xw<0, 2><<<gg, 256, 0, stream>>>(x, wv, bv, Vt, 8192, 2048, 2048);

    rope_kernel<<<32768, 256, 0, stream>>>(Qb, Kb);
    attn_kernel<<<dim3(64, 32), 256, 0, stream>>>(Qb, Kb, Vt);

    // output projection: f32 store (reference output dtype is float32)
    gemm_xw<1, 0><<<gg, 256, 0, stream>>>(Qb, wd, bd, d_out, 8192, 2048, 2048);
    (void)in_sizes; (void)n_in; (void)out_size; (void)ws_size;
}

// Round 5
// 684.111 us; speedup vs baseline: 1.2820x; 1.2820x over previous
//
#include <hip/hip_runtime.h>
#include <hip/hip_bf16.h>
#include <stdint.h>

typedef __attribute__((ext_vector_type(8))) short short8;
typedef __attribute__((ext_vector_type(4))) float floatx4;

#define AS1 __attribute__((address_space(1)))
#define AS3 __attribute__((address_space(3)))

// async global->LDS, 16B/lane. HW dest = wave-uniform base + lane*16, so every
// call site ensures its lane's dst == base + lane*16 (contiguous by lane).
__device__ __forceinline__ void async_copy16(const void* g, void* l) {
    __builtin_amdgcn_global_load_lds((const AS1 uint32_t*)(uintptr_t)g,
                                     (AS3 uint32_t*)(uintptr_t)l, 16, 0, 0);
}

// LDS swizzle: 64B rows of 4x16B chunks; logical chunk c of row r lives at
// phys chunk c ^ ((r>>1)&3).  Reads become 2-way bank aliasing (free, m136).
// Staging (r = base + lane>>2, phys chunk forced = lane&3 by async contiguity)
// fetches source chunk (lane&3)^((lane>>3)&3); sync writes use same expr as dst.

// load 8 f32 -> 8 bf16 packed
__device__ __forceinline__ short8 cvt8(const float* p) {
    float4 a = *(const float4*)p;
    float4 b = *(const float4*)(p + 4);
    union { short s[8]; short8 v; } u;
    __hip_bfloat16* h = (__hip_bfloat16*)u.s;
    h[0] = __float2bfloat16(a.x); h[1] = __float2bfloat16(a.y);
    h[2] = __float2bfloat16(a.z); h[3] = __float2bfloat16(a.w);
    h[4] = __float2bfloat16(b.x); h[5] = __float2bfloat16(b.y);
    h[6] = __float2bfloat16(b.z); h[7] = __float2bfloat16(b.w);
    return u.v;
}

// ---------------------------------------------------------------- cvt f32->bf16
__global__ __launch_bounds__(256) void cvt_bf16(const float* __restrict__ s,
                                                __hip_bfloat16* __restrict__ d, int n) {
    int i = ((int)blockIdx.x * 256 + (int)threadIdx.x) * 4;
    if (i >= n) return;
    const float4 v = *(const float4*)(s + i);
    ushort4 pk;
    __hip_bfloat16* ph = (__hip_bfloat16*)&pk;
    ph[0] = __float2bfloat16(v.x); ph[1] = __float2bfloat16(v.y);
    ph[2] = __float2bfloat16(v.z); ph[3] = __float2bfloat16(v.w);
    *(ushort4*)(d + i) = pk;
}

// ---------------------------------------------------------------- GEMM
// C = A @ Bt^T + bias. 128x128 tile, BK=32, 4 waves 2x2.
// A_ASYNC: 1 -> A is bf16, staged via global_load_lds; 0 -> A f32, sync cvt.
// B_ASYNC: same for B. STORE_MODE: 0 f32; 1 bf16; 2 bf16 V-transpose
//   (row=t,col=hid) -> Vt[(b*16+nh)*128+d][s], s=t>>2,b=t&3,nh=col>>7,d=col&127.
template <int A_ASYNC, int B_ASYNC, int STORE_MODE>
__global__ __launch_bounds__(256, 2) void gemm_k(const void* __restrict__ Av,
                                                 const void* __restrict__ Bv,
                                                 const float* __restrict__ bias,
                                                 void* __restrict__ Cv,
                                                 int M, int N, int K) {
    __shared__ __align__(16) __hip_bfloat16 sA[128 * 32];
    __shared__ __align__(16) __hip_bfloat16 sB[128 * 32];
    const int tid  = threadIdx.x;
    const int wave = tid >> 6, lane = tid & 63;
    const int quad = lane >> 4, l16 = lane & 15;
    const int m0 = blockIdx.x * 128, n0 = blockIdx.y * 128;
    const int wm = (wave >> 1) * 64, wn = (wave & 1) * 64;
    const int lrow   = lane >> 2;
    const int srcoff = (((lane & 3) ^ ((lane >> 3) & 3)) * 16);  // swizzled chunk, bytes
    const int dstoff = (lane & 3) * 16;                          // phys chunk, bytes
    const int swzq   = (quad ^ ((l16 >> 1) & 3)) * 16;           // fragment chunk, bytes

    floatx4 acc[4][4];
#pragma unroll
    for (int i = 0; i < 4; i++)
#pragma unroll
        for (int j = 0; j < 4; j++) acc[i][j] = (floatx4)0.0f;

    for (int k0 = 0; k0 < K; k0 += 32) {
        short8 va[2], vb[2];
#pragma unroll
        for (int c = 0; c < 2; ++c) {  // pre-barrier global loads for sync operands
            int r = wave * 32 + c * 16 + lrow;
            if (!A_ASYNC) va[c] = cvt8((const float*)Av + (size_t)(m0 + r) * K + k0 + (lane & 3) * 8);
            if (!B_ASYNC) vb[c] = cvt8((const float*)Bv + (size_t)(n0 + r) * K + k0 + (lane & 3) * 8);
        }
        __syncthreads();  // prior iteration's fragment reads done
#pragma unroll
        for (int c = 0; c < 2; ++c) {
            int r = wave * 32 + c * 16 + lrow;
            if (A_ASYNC)
                async_copy16((const char*)((const __hip_bfloat16*)Av + (size_t)(m0 + r) * K + k0) + srcoff,
                             (char*)sA + r * 64 + dstoff);
            else
                *(short8*)((char*)sA + r * 64 + srcoff) = va[c];
            if (B_ASYNC)
                async_copy16((const char*)((const __hip_bfloat16*)Bv + (size_t)(n0 + r) * K + k0) + srcoff,
                             (char*)sB + r * 64 + dstoff);
            else
                *(short8*)((char*)sB + r * 64 + srcoff) = vb[c];
        }
        __syncthreads();  // drain staging (vmcnt/lgkm before barrier)

        short8 af[4], bf[4];
#pragma unroll
        for (int i = 0; i < 4; i++)
            af[i] = *(const short8*)((const char*)sA + (wm + i * 16 + l16) * 64 + swzq);
#pragma unroll
        for (int j = 0; j < 4; j++)
            bf[j] = *(const short8*)((const char*)sB + (wn + j * 16 + l16) * 64 + swzq);
#pragma unroll
        for (int i = 0; i < 4; i++)
#pragma unroll
            for (int j = 0; j < 4; j++)
                acc[i][j] = __builtin_amdgcn_mfma_f32_16x16x32_bf16(af[i], bf[j], acc[i][j], 0, 0, 0);
    }

#pragma unroll
    for (int i = 0; i < 4; i++) {
#pragma unroll
        for (int j = 0; j < 4; j++) {
            int col  = n0 + wn + j * 16 + l16;
            float bv = bias[col];
#pragma unroll
            for (int r = 0; r < 4; ++r) {
                int row = m0 + wm + i * 16 + quad * 4 + r;  // C-layout: row=quad*4+reg
                float v = acc[i][j][r] + bv;
                if (STORE_MODE == 0) {
                    ((float*)Cv)[(size_t)row * N + col] = v;
                } else if (STORE_MODE == 1) {
                    ((__hip_bfloat16*)Cv)[(size_t)row * N + col] = __float2bfloat16(v);
                } else {
                    int s = row >> 2, b = row & 3, nh = col >> 7, d = col & 127;
                    ((__hip_bfloat16*)Cv)[((size_t)(b * 16 + nh) * 128 + d) * 2048 + s] =
                        __float2bfloat16(v);
                }
            }
        }
    }
}

// ---------------------------------------------------------------- RoPE (in-place)
__global__ __launch_bounds__(256) void rope_kernel(__hip_bfloat16* __restrict__ Q,
                                                   __hip_bfloat16* __restrict__ K) {
    const int PER = 8192 * 16 * 32;
    int idx = (int)blockIdx.x * 256 + (int)threadIdx.x;
    __hip_bfloat16* base = (idx < PER) ? Q : K;
    int i  = (idx < PER) ? idx : idx - PER;
    int p  = i & 31;
    int nh = (i >> 5) & 15;
    int t  = i >> 9;
    int s  = t >> 2;
    float inv = __expf(-(float)(p & 15) * 0.5756462732485115f);  // ln(10000)/16
    float ang = (float)s * inv;
    float c = cosf(ang), sn = sinf(ang);
    size_t off = (size_t)t * 2048 + nh * 128 + 2 * p;
    float x0 = __bfloat162float(base[off]);
    float x1 = __bfloat162float(base[off + 1]);
    base[off]     = __float2bfloat16(x0 * c - x1 * sn);
    base[off + 1] = __float2bfloat16(x0 * sn + x1 * c);
}

// ---------------------------------------------------------------- flash attention
// Qio [t][2048] (roped; O overwrites in place), Km [t][2048], Vt [bh][128][2048].
// Block (bh, qt): 128 q-rows, 64 kv/iter; wave owns 32 q rows (2 m-groups).
// Q fragments cached in registers (loaded once); K/V staged async+swizzled.
__global__ __launch_bounds__(256, 2) void attn_kernel(__hip_bfloat16* __restrict__ Qio,
                                                      const __hip_bfloat16* __restrict__ Km,
                                                      const __hip_bfloat16* __restrict__ Vt) {
    __shared__ __align__(16) __hip_bfloat16 sK[4][64][32];   // [d-chunk][kv][32d]
    __shared__ __align__(16) __hip_bfloat16 sV[2][128][32];  // [kv-chunk][d][32kv]
    __shared__ __align__(16) __hip_bfloat16 sP[2][128][32];  // [kv-chunk][q][32kv]
    const int tid  = threadIdx.x;
    const int wave = tid >> 6, lane = tid & 63;
    const int quad = lane >> 4, l16 = lane & 15;
    const int bh = blockIdx.x, b = bh >> 4, nh = bh & 15;
    const int qtl = 15 - (int)blockIdx.y;  // longest blocks first
    const int q0  = qtl * 128;
    const int lrow   = lane >> 2;
    const int srcoff = (((lane & 3) ^ ((lane >> 3) & 3)) * 16);
    const int dstoff = (lane & 3) * 16;
    const int swzq   = (quad ^ ((l16 >> 1) & 3)) * 16;
    const float scale = 0.08838834764831845f;  // 1/sqrt(128)

    // Q fragments in registers: rows wave*32 + mg*16 + l16, k = kk*32 + quad*8 + j
    short8 qf[2][4];
#pragma unroll
    for (int mg = 0; mg < 2; ++mg)
#pragma unroll
        for (int kk = 0; kk < 4; ++kk) {
            int qrow = wave * 32 + mg * 16 + l16;
            int t    = (q0 + qrow) * 4 + b;
            qf[mg][kk] = *(const short8*)(Qio + (size_t)t * 2048 + nh * 128 + kk * 32 + quad * 8);
        }

    float m_i[2][4], l_i[2][4];
#pragma unroll
    for (int mg = 0; mg < 2; ++mg)
#pragma unroll
        for (int r = 0; r < 4; ++r) { m_i[mg][r] = -1e30f; l_i[mg][r] = 0.f; }
    floatx4 o_acc[2][8];
#pragma unroll
    for (int mg = 0; mg < 2; ++mg)
#pragma unroll
        for (int n = 0; n < 8; ++n) o_acc[mg][n] = (floatx4)0.0f;

    const int nk = 2 * qtl + 2;
    for (int kt = 0; kt < nk; ++kt) {
        __syncthreads();  // prior iter's sK/sV/sP reads done
        {
            const int kc = wave >> 1, dh = (wave & 1) * 64;
#pragma unroll
            for (int c = 0; c < 4; ++c) {
                int krow = c * 16 + lrow;
                int t    = (kt * 64 + krow) * 4 + b;
                async_copy16((const char*)(Km + (size_t)t * 2048 + nh * 128 + wave * 32) + srcoff,
                             (char*)&sK[wave][0][0] + krow * 64 + dstoff);
            }
#pragma unroll
            for (int c = 0; c < 4; ++c) {
                int d = dh + c * 16 + lrow;
                async_copy16((const char*)(Vt + ((size_t)bh * 128 + d) * 2048 + kt * 64 + kc * 32) + srcoff,
                             (char*)&sV[kc][0][0] + d * 64 + dstoff);
            }
        }
        __syncthreads();  // drain staging

        // S = Q K^T (both m-groups share the K fragments)
        floatx4 sacc[2][4];
#pragma unroll
        for (int mg = 0; mg < 2; ++mg)
#pragma unroll
            for (int n = 0; n < 4; ++n) sacc[mg][n] = (floatx4)0.0f;
#pragma unroll
        for (int kk = 0; kk < 4; ++kk)
#pragma unroll
            for (int nt = 0; nt < 4; ++nt) {
                short8 bk = *(const short8*)((const char*)&sK[kk][0][0] + (nt * 16 + l16) * 64 + swzq);
                sacc[0][nt] = __builtin_amdgcn_mfma_f32_16x16x32_bf16(qf[0][kk], bk, sacc[0][nt], 0, 0, 0);
                sacc[1][nt] = __builtin_amdgcn_mfma_f32_16x16x32_bf16(qf[1][kk], bk, sacc[1][nt], 0, 0, 0);
            }

        // online softmax per m-group; P -> sP (swizzled chunks)
#pragma unroll
        for (int mg = 0; mg < 2; ++mg) {
            const int qbase = wave * 32 + mg * 16 + quad * 4;  // local q row base
            const bool dmask = (kt * 64 + 63) > (q0 + wave * 32 + mg * 16);
            float sv[4][4], mx[4];
#pragma unroll
            for (int r = 0; r < 4; ++r) mx[r] = -1e30f;
#pragma unroll
            for (int nt = 0; nt < 4; ++nt)
#pragma unroll
                for (int r = 0; r < 4; ++r) {
                    float v = sacc[mg][nt][r] * scale;
                    if (dmask && (kt * 64 + nt * 16 + l16 > q0 + qbase + r)) v = -1e30f;
                    sv[nt][r] = v;
                    mx[r] = fmaxf(mx[r], v);
                }
#pragma unroll
            for (int off = 1; off < 16; off <<= 1)
#pragma unroll
                for (int r = 0; r < 4; ++r) mx[r] = fmaxf(mx[r], __shfl_xor(mx[r], off, 64));

            float alpha[4], mnew[4], rsum[4];
#pragma unroll
            for (int r = 0; r < 4; ++r) {
                mnew[r]  = fmaxf(m_i[mg][r], mx[r]);
                alpha[r] = __expf(m_i[mg][r] - mnew[r]);
                rsum[r]  = 0.f;
            }
#pragma unroll
            for (int nt = 0; nt < 4; ++nt)
#pragma unroll
                for (int r = 0; r < 4; ++r) {
                    float p = __expf(sv[nt][r] - mnew[r]);
                    rsum[r] += p;
                    int ql = qbase + r;
                    int e  = nt * 16 + l16;
                    int e32 = e & 31;
                    int phys = (e32 >> 3) ^ ((ql >> 1) & 3);
                    sP[e >> 5][ql][phys * 8 + (e32 & 7)] = __float2bfloat16(p);
                }
#pragma unroll
            for (int off = 1; off < 16; off <<= 1)
#pragma unroll
                for (int r = 0; r < 4; ++r) rsum[r] += __shfl_xor(rsum[r], off, 64);
#pragma unroll
            for (int r = 0; r < 4; ++r) {
                l_i[mg][r] = l_i[mg][r] * alpha[r] + rsum[r];
                m_i[mg][r] = mnew[r];
            }
#pragma unroll
            for (int n = 0; n < 8; ++n)
#pragma unroll
                for (int r = 0; r < 4; ++r) o_acc[mg][n][r] *= alpha[r];
        }
        __syncthreads();  // sP writes ordered & visible before PV reads

        // O += P V
#pragma unroll
        for (int kc = 0; kc < 2; ++kc) {
            short8 ap0 = *(const short8*)((const char*)&sP[kc][0][0] + (wave * 32 + l16) * 64 + swzq);
            short8 ap1 = *(const short8*)((const char*)&sP[kc][0][0] + (wave * 32 + 16 + l16) * 64 + swzq);
#pragma unroll
            for (int nt = 0; nt < 8; ++nt) {
                short8 bv = *(const short8*)((const char*)&sV[kc][0][0] + (nt * 16 + l16) * 64 + swzq);
                o_acc[0][nt] = __builtin_amdgcn_mfma_f32_16x16x32_bf16(ap0, bv, o_acc[0][nt], 0, 0, 0);
                o_acc[1][nt] = __builtin_amdgcn_mfma_f32_16x16x32_bf16(ap1, bv, o_acc[1][nt], 0, 0, 0);
            }
        }
    }

    // write O in place over this block's own Q region
#pragma unroll
    for (int mg = 0; mg < 2; ++mg)
#pragma unroll
        for (int nt = 0; nt < 8; ++nt)
#pragma unroll
            for (int r = 0; r < 4; ++r) {
                int s = q0 + wave * 32 + mg * 16 + quad * 4 + r;
                int t = s * 4 + b;
                int col = nh * 128 + nt * 16 + l16;
                Qio[(size_t)t * 2048 + col] = __float2bfloat16(o_acc[mg][nt][r] / l_i[mg][r]);
            }
}

// ---------------------------------------------------------------- launch
extern "C" void kernel_launch(void* const* d_in, const int* in_sizes, int n_in,
                              void* d_out, int out_size, void* d_ws, size_t ws_size,
                              hipStream_t stream) {
    const float* x  = (const float*)d_in[0];
    const float* wq = (const float*)d_in[1];
    const float* bq = (const float*)d_in[2];
    const float* wk = (const float*)d_in[3];
    const float* bk = (const float*)d_in[4];
    const float* wv = (const float*)d_in[5];
    const float* bv = (const float*)d_in[6];
    const float* wd = (const float*)d_in[7];
    const float* bd = (const float*)d_in[8];
    // d_in[9] = start_pos: unused (reference recomputes t=arange(seq))

    const size_t TH = (size_t)8192 * 2048;  // 16.7M elems
    const size_t HH = (size_t)2048 * 2048;  // 4M elems
    dim3 gg(64, 16);

    if (ws_size >= (136ull << 20)) {
        // spacious: pre-convert to bf16, all GEMMs fully async (m97-style)
        __hip_bfloat16* xb  = (__hip_bfloat16*)d_ws;
        __hip_bfloat16* Qb  = xb + TH;
        __hip_bfloat16* Kb  = Qb + TH;
        __hip_bfloat16* Vtb = Kb + TH;
        __hip_bfloat16* wb  = Vtb + TH;  // reused per GEMM

        cvt_bf16<<<(int)(TH / 1024), 256, 0, stream>>>(x, xb, (int)TH);
        cvt_bf16<<<(int)(HH / 1024), 256, 0, stream>>>(wq, wb, (int)HH);
        gemm_k<1, 1, 1><<<gg, 256, 0, stream>>>(xb, wb, bq, Qb, 8192, 2048, 2048);
        cvt_bf16<<<(int)(HH / 1024), 256, 0, stream>>>(wk, wb, (int)HH);
        gemm_k<1, 1, 1><<<gg, 256, 0, stream>>>(xb, wb, bk, Kb, 8192, 2048, 2048);
        cvt_bf16<<<(int)(HH / 1024), 256, 0, stream>>>(wv, wb, (int)HH);
        gemm_k<1, 1, 2><<<gg, 256, 0, stream>>>(xb, wb, bv, Vtb, 8192, 2048, 2048);

        rope_kernel<<<32768, 256, 0, stream>>>(Qb, Kb);
        attn_kernel<<<dim3(64, 16), 256, 0, stream>>>(Qb, Kb, Vtb);

        cvt_bf16<<<(int)(HH / 1024), 256, 0, stream>>>(wd, wb, (int)HH);
        gemm_k<1, 1, 0><<<gg, 256, 0, stream>>>(Qb, wb, bd, d_out, 8192, 2048, 2048);
    } else {
        // tight (96 MiB total scratch): Q in ws; K,Vt inside d_out
        __hip_bfloat16* Qb = (__hip_bfloat16*)d_ws;
        __hip_bfloat16* Kb = (__hip_bfloat16*)d_out;
        __hip_bfloat16* Vt = (__hip_bfloat16*)d_out + TH;

        gemm_k<0, 0, 1><<<gg, 256, 0, stream>>>(x, wq, bq, Qb, 8192, 2048, 2048);
        gemm_k<0, 0, 1><<<gg, 256, 0, stream>>>(x, wk, bk, Kb, 8192, 2048, 2048);
        gemm_k<0, 0, 2><<<gg, 256, 0, stream>>>(x, wv, bv, Vt, 8192, 2048, 2048);

        rope_kernel<<<32768, 256, 0, stream>>>(Qb, Kb);
        attn_kernel<<<dim3(64, 16), 256, 0, stream>>>(Qb, Kb, Vt);

        // final projection: A (attn out) is bf16 -> async; B stays f32 sync-cvt
        gemm_k<1, 0, 0><<<gg, 256, 0, stream>>>(Qb, wd, bd, d_out, 8192, 2048, 2048);
    }
    (void)in_sizes; (void)n_in; (void)out_size; (void)ws_size;
}